// Round 6
// baseline (773.946 us; speedup 1.0000x reference)
//
#include <hip/hip_runtime.h>
#include <math.h>
#include <stdint.h>

// ConvLSTM (Seq2VecRNN2D) round 6: round-5 structure + 1-stage register pipeline
// (read frags[lin+1] while MFMAing frags[lin]); W staged 3-ahead in 4 LDS slots.
// 3-term bf16-split MFMA, fused LSTM cell. B=8 T=8 CIN=128 HID=64 G=256 H=W=32.
//
// Activation image per (slot,b,cg32): [34 y'][34 px][8 blk of 16B], blk = pl*4+kg
// stored at blk^(px&7); ch = cg*32+kg*8+j, pl0=hi bf16, pl1=lo bf16. Borders zero.
// Weight image per (combo,cg,tap,nt): [pl][4 g][16 hcp][8 b8 of 16B], b8 = kg+4*(hc&1)
// stored at b8^(hcp&7); hcp = hc_local>>1.
//
// Schedule per window lin: wait vmcnt(K); barrier; stage W[lin+3] -> slot (lin+3)%4;
// (tap0: stage A[cg+1] -> parity (cg+1)&1); read frags[lin+1]; MFMA frags[lin].
// K = 6 at taps 1,2 (prev windows carried the tap0 A-burst), else 2 (in-order
// vmcnt retirement; W[lin+1] needed by this window's reads was staged at lin-2).

typedef __attribute__((ext_vector_type(8))) short short8;
typedef __attribute__((ext_vector_type(4))) float float4v;

namespace {
constexpr int IMG = 34 * 34 * 64;            // u16 per (slot,b,cg) image
constexpr size_t SLOTI = 16ull * IMG;        // u16 per h slot (8 b x 2 cg)
constexpr int ROWB = 34 * 128;               // bytes per image row (4352)
constexpr int PADB = 8192;                   // tail slack for DMA overshoot
}
template <int N> struct IC { static constexpr int v = N; };

__device__ __forceinline__ uint16_t bf16_rne(float x) {
  uint32_t u = __builtin_bit_cast(uint32_t, x);
  return (uint16_t)((u + 0x7FFFu + ((u >> 16) & 1u)) >> 16);
}
__device__ __forceinline__ float bf16_to_f(uint16_t h) {
  uint32_t u = ((uint32_t)h) << 16;
  return __builtin_bit_cast(float, u);
}

__device__ __forceinline__ void gl_lds16(const void* g, void* l) {
  __builtin_amdgcn_global_load_lds(
      (const __attribute__((address_space(1))) void*)g,
      (__attribute__((address_space(3))) void*)l, 16, 0, 0);
}

// ---- feature pack: fp32 [B][T][128][32][32] -> swizzled images [t][b][4cg] ----
__global__ void pack_features(const float* __restrict__ f, uint16_t* __restrict__ out) {
  const size_t i = (size_t)blockIdx.x * 256 + threadIdx.x;  // 16B-block index, < 2367488
  const int blk_s = (int)(i & 7);
  size_t pp = i >> 3;
  const int px = (int)(pp % 34); pp /= 34;
  const int yy = (int)(pp % 34); pp /= 34;
  const int cg = (int)(pp & 3);
  const int bt = (int)(pp >> 2);
  const int b = bt & 7, t = bt >> 3;
  const int blk = blk_s ^ (px & 7);
  const int pl = blk >> 2, kg = blk & 3;
  short8 sv;
  if (px == 0 || px == 33 || yy == 0 || yy == 33) {
    #pragma unroll
    for (int j = 0; j < 8; ++j) sv[j] = 0;
  } else {
    const int x = px - 1, y = yy - 1;
    #pragma unroll
    for (int j = 0; j < 8; ++j) {
      const int ch = cg * 32 + kg * 8 + j;
      const float fv = f[(((size_t)b * 8 + t) * 128 + ch) * 1024 + y * 32 + x];
      const uint16_t hi = bf16_rne(fv);
      sv[j] = (short)(pl ? bf16_rne(fv - bf16_to_f(hi)) : hi);
    }
  }
  *(short8*)(out + i * 8) = sv;
}

// ---- weight pack into swizzled images: per combo [cg][tap][nt][4096 u32] ----
struct WPackArgs {
  const float* wih[4]; const float* whh[4];
  const float* bih[4]; const float* bhh[4];
  uint32_t* wp; float* bp;
};
__global__ void pack_weights(WPackArgs A) {
  const int combo = blockIdx.y;
  const int idx = blockIdx.x * 256 + threadIdx.x;  // < 442368
  const int q = idx & 4095;
  const int rest = idx >> 12;
  const int nt = rest & 1;
  const int ct = rest >> 1;          // cg*9+tap
  const int tap = ct % 9, cg = ct / 9;
  const int w2 = q & 3;
  const int b8s = (q >> 2) & 7;
  const int hcp = (q >> 5) & 15;
  const int g = (q >> 9) & 3;
  const int pl = (q >> 11) & 1;
  const int b8 = b8s ^ (hcp & 7);
  const int kg = b8 & 3;
  const int hcl = hcp * 2 + (b8 >> 2);
  const int n = g * 64 + nt * 32 + hcl;
  const float* wih = A.wih[combo];
  const float* whh = A.whh[combo];
  uint32_t out = 0;
  #pragma unroll
  for (int e = 0; e < 2; ++e) {
    const int ch = cg * 32 + kg * 8 + w2 * 2 + e;
    const float wv = (ch < 128) ? wih[((size_t)n * 128 + ch) * 9 + tap]
                                : whh[((size_t)n * 64 + (ch - 128)) * 9 + tap];
    const uint16_t hi = bf16_rne(wv);
    const uint16_t v = pl ? bf16_rne(wv - bf16_to_f(hi)) : hi;
    out |= ((uint32_t)v) << (16 * e);
  }
  A.wp[(size_t)combo * 442368 + idx] = out;
  if (idx < 256) A.bp[combo * 256 + idx] = A.bih[combo][idx] + A.bhh[combo][idx];
}

struct StepArgs {
  const uint16_t* in0; const uint16_t* in1; const uint16_t* in2;  // images
  int nc0, nc1, nc2;         // cg counts per tensor
  const uint32_t* W;         // combo base: [cg][tap][nt][4096 u32]
  const float* bias;         // [256], n = gate*64+hc
  float* cbuf;               // plain fp32 [b][64][1024]
  uint16_t* himg;            // nullable: [b][2 cg][IMG]
  float* hf32;               // nullable: plain [b][64][1024]
};

struct Frags { short8 a[2][2]; short8 w[2][4]; };

// Block: b = bx>>4, 4-row band (bx>>1)&7, nt = bx&1. 512 threads = 8 waves;
// wave w: row r = w&3, hc-subgroup hcg = w>>2. Per wave: 2 x-halves x 4 gates.
__global__ __launch_bounds__(512, 2) void conv_lstm_step(StepArgs A0, StepArgs A1) {
  extern __shared__ char smem[];
  char* Asm_ = smem;               // 2 x 32768 (A double-buffer; 26112 used each)
  char* Wsm_ = smem + 65536;       // 4 x 16384 (W quad-buffer)

  const StepArgs a = (blockIdx.z == 0) ? A0 : A1;
  const int bx = blockIdx.x;
  const int nt = bx & 1;
  const int band = (bx >> 1) & 7;
  const int b = bx >> 4;
  const int y0 = band * 4;
  const int tid = threadIdx.x;
  const int lane = tid & 63;
  const int w = tid >> 6;
  const int m15 = lane & 15;
  const int kg = lane >> 4;
  const int r = w & 3;
  const int hcg = w >> 2;

  // fragment read offsets (bytes), conflict-free via baked swizzle
  int offA[2][3][2];
  #pragma unroll
  for (int xh = 0; xh < 2; ++xh)
    #pragma unroll
    for (int kx = 0; kx < 3; ++kx)
      #pragma unroll
      for (int pl = 0; pl < 2; ++pl) {
        const int px = xh * 16 + kx + m15;
        const int sw = (pl * 4 + kg) ^ (px & 7);
        offA[xh][kx][pl] = r * ROWB + px * 128 + sw * 16;
      }
  int offW[2][4];
  {
    const int hcp = hcg * 8 + (m15 >> 1);
    const int b8 = kg + 4 * (m15 & 1);
    #pragma unroll
    for (int pl = 0; pl < 2; ++pl)
      #pragma unroll
      for (int g = 0; g < 4; ++g)
        offW[pl][g] = (((pl * 4 + g) * 16 + hcp) * 8 + (b8 ^ (hcp & 7))) * 16;
  }

  const int ncg = a.nc0 + a.nc1 + a.nc2;
  auto abase = [&](int cg) -> const char* {
    const uint16_t* t;
    if (cg < a.nc0) t = a.in0 + ((size_t)b * a.nc0 + cg) * IMG;
    else if (cg < a.nc0 + a.nc1) t = a.in1 + ((size_t)b * a.nc1 + (cg - a.nc0)) * IMG;
    else t = a.in2 + ((size_t)b * a.nc2 + (cg - a.nc0 - a.nc1)) * IMG;
    return (const char*)t + (size_t)y0 * ROWB;
  };
  // 4 chunks/wave (32 KB; 26112 used, tail lands in dead LDS; source has PADB slack)
  auto stageA = [&](int cgi, int par) {
    const char* g = abase(cgi);
    char* d = Asm_ + par * 32768;
    #pragma unroll
    for (int j = 0; j < 4; ++j)
      gl_lds16(g + (size_t)(4 * w + j) * 1024 + lane * 16, d + (4 * w + j) * 1024);
  };
  // 2 chunks/wave (16 KB tile)
  auto stageW = [&](int cgs, int taps, int slot) {
    const char* g = (const char*)a.W + ((size_t)((cgs * 9 + taps) * 2 + nt) << 14);
    char* d = Wsm_ + slot * 16384;
    #pragma unroll
    for (int j = 0; j < 2; ++j)
      gl_lds16(g + (size_t)(2 * w + j) * 1024 + lane * 16, d + (2 * w + j) * 1024);
  };
  // read fragments for window lin1 = cg*9+tap (compile-time tap)
  auto read_frags = [&](auto tapc, int cgn, int lin1) -> Frags {
    constexpr int TN = decltype(tapc)::v;
    constexpr int ky = TN / 3, kx = TN % 3;
    Frags f;
    const char* Ab = Asm_ + (cgn & 1) * 32768 + ky * ROWB;
    const char* Wb = Wsm_ + (lin1 & 3) * 16384;
    #pragma unroll
    for (int xh = 0; xh < 2; ++xh)
      #pragma unroll
      for (int pl = 0; pl < 2; ++pl)
        f.a[xh][pl] = *(const short8*)(Ab + offA[xh][kx][pl]);
    #pragma unroll
    for (int pl = 0; pl < 2; ++pl)
      #pragma unroll
      for (int g = 0; g < 4; ++g)
        f.w[pl][g] = *(const short8*)(Wb + offW[pl][g]);
    return f;
  };

  float4v acc[2][4];
  #pragma unroll
  for (int xh = 0; xh < 2; ++xh)
    #pragma unroll
    for (int g = 0; g < 4; ++g) acc[xh][g] = (float4v){0.f, 0.f, 0.f, 0.f};

  // Prologue: A[0]; W[0..2] -> slots 0..2. vmcnt(2) leaves only W[2] in flight,
  // so A[0], W[0], W[1] have landed; then read frags[0].
  stageA(0, 0);
  stageW(0, 0, 0);
  stageW(0, 1, 1);
  stageW(0, 2, 2);
  asm volatile("s_waitcnt vmcnt(2)\n\ts_barrier" ::: "memory");
  Frags cur = read_frags(IC<0>{}, 0, 0);

  for (int cg = 0; cg < ncg; ++cg) {
    auto tap_body = [&](auto tapc) {
      constexpr int TAP = decltype(tapc)::v;
      constexpr int CNT = (TAP == 1 || TAP == 2) ? 6 : 2;
      asm volatile("s_waitcnt vmcnt(%0)\n\ts_barrier" :: "n"(CNT) : "memory");
      const int lin = cg * 9 + TAP;
      {  // stage W for lin+3 (wrap to a dead-but-valid tile near the end)
        const int l3 = lin + 3;
        int cgs = l3 / 9;
        const int taps = l3 % 9;
        if (cgs >= ncg) cgs = 0;
        stageW(cgs, taps, l3 & 3);
      }
      if (TAP == 0) {  // stage next cg's A into the other parity
        const int nx = (cg + 1 < ncg) ? cg + 1 : 0;
        stageA(nx, (cg + 1) & 1);
      }
      // read next window's fragments (independent of this window's MFMAs)
      constexpr int TN = (TAP + 1) % 9;
      Frags nxt = read_frags(IC<TN>{}, cg + (TAP == 8 ? 1 : 0), lin + 1);
      // MFMA with pipelined fragments
      #pragma unroll
      for (int xh = 0; xh < 2; ++xh)
        #pragma unroll
        for (int g = 0; g < 4; ++g) {
          acc[xh][g] = __builtin_amdgcn_mfma_f32_16x16x32_bf16(cur.a[xh][0], cur.w[0][g], acc[xh][g], 0, 0, 0);
          acc[xh][g] = __builtin_amdgcn_mfma_f32_16x16x32_bf16(cur.a[xh][0], cur.w[1][g], acc[xh][g], 0, 0, 0);
          acc[xh][g] = __builtin_amdgcn_mfma_f32_16x16x32_bf16(cur.a[xh][1], cur.w[0][g], acc[xh][g], 0, 0, 0);
        }
      cur = nxt;
    };
    tap_body(IC<0>{}); tap_body(IC<1>{}); tap_body(IC<2>{});
    tap_body(IC<3>{}); tap_body(IC<4>{}); tap_body(IC<5>{});
    tap_body(IC<6>{}); tap_body(IC<7>{}); tap_body(IC<8>{});
  }
  asm volatile("s_waitcnt vmcnt(0)" ::: "memory");  // drain dummy restages

  // ---- fused LSTM cell epilogue ----
  const int hcl = hcg * 16 + m15;
  const int hc = nt * 32 + hcl;
  const int y = y0 + r;
  float bi[4];
  #pragma unroll
  for (int g = 0; g < 4; ++g) bi[g] = a.bias[g * 64 + hc];
  float* crow = a.cbuf + ((size_t)(b * 64 + hc)) * 1024 + y * 32;
  float* hrow = a.hf32 ? a.hf32 + ((size_t)(b * 64 + hc)) * 1024 + y * 32 : nullptr;
  uint16_t* hb = a.himg ? a.himg + ((size_t)(b * 2 + nt)) * IMG : nullptr;
  const int kgb = hcl >> 3, jj = hcl & 7;
  #pragma unroll
  for (int xh = 0; xh < 2; ++xh) {
    const int x0 = xh * 16 + kg * 4;
    float4v cv = *(float4v*)(crow + x0);
    float4v cn, hn;
    #pragma unroll
    for (int q = 0; q < 4; ++q) {
      const float ig = 1.f / (1.f + expf(-(acc[xh][0][q] + bi[0])));
      const float fg = 1.f / (1.f + expf(-(acc[xh][1][q] + bi[1])));
      const float gg = tanhf(acc[xh][2][q] + bi[2]);
      const float og = 1.f / (1.f + expf(-(acc[xh][3][q] + bi[3])));
      const float c2 = fg * cv[q] + ig * gg;
      cn[q] = c2;
      hn[q] = og * tanhf(c2);
    }
    *(float4v*)(crow + x0) = cn;
    if (hrow) *(float4v*)(hrow + x0) = hn;
    if (hb) {
      #pragma unroll
      for (int q = 0; q < 4; ++q) {
        const int px = x0 + q + 1;
        const int sw = px & 7;
        const uint16_t hi = bf16_rne(hn[q]);
        const uint16_t lo = bf16_rne(hn[q] - bf16_to_f(hi));
        const size_t p16 = ((size_t)(y + 1) * 34 + px) * 64;
        hb[p16 + (size_t)(kgb ^ sw) * 8 + jj] = hi;
        hb[p16 + (size_t)((4 + kgb) ^ sw) * 8 + jj] = lo;
      }
    }
  }
  if (hb) {   // keep image borders zero (ws is re-poisoned every call)
    {
      const int rr = tid >> 7;             // 0..3
      const int hlf = (tid >> 6) & 1;
      const int jx = tid & 63;
      hb[((size_t)(y0 + 1 + rr) * 34 + hlf * 33) * 64 + jx] = 0;
    }
    if (band == 0) for (int i = tid; i < 2176; i += 512) hb[i] = 0;
    if (band == 7) for (int i = tid; i < 2176; i += 512) hb[(size_t)33 * 2176 + i] = 0;
  }
}

// out[b][o][p] = relu(b_out[o] + sum_c w_out[o][c] * last[b][c][p])  (fp32 inputs)
__global__ void final_conv(const float* __restrict__ h1f_last, const float* __restrict__ h1r_last,
                           const float* __restrict__ wout, const float* __restrict__ bout,
                           float* __restrict__ out) {
  __shared__ float Ws[16 * 128];
  const int oq = blockIdx.y;
  for (int i = threadIdx.x; i < 16 * 128; i += 256) Ws[i] = wout[oq * 16 * 128 + i];
  __syncthreads();
  const int gp = blockIdx.x * 256 + threadIdx.x;
  const int b = gp >> 10, p = gp & 1023;
  float acc[16];
  #pragma unroll
  for (int o = 0; o < 16; ++o) acc[o] = bout[oq * 16 + o];
  for (int c = 0; c < 128; ++c) {
    const float xv = (c < 64) ? h1f_last[((size_t)b * 64 + c) * 1024 + p]
                              : h1r_last[((size_t)b * 64 + (c - 64)) * 1024 + p];
    #pragma unroll
    for (int o = 0; o < 16; ++o) acc[o] = fmaf(xv, Ws[o * 128 + c], acc[o]);
  }
  #pragma unroll
  for (int o = 0; o < 16; ++o) {
    const float v = acc[o];
    out[((size_t)b * 64 + oq * 16 + o) * 1024 + p] = v > 0.f ? v : 0.f;
  }
}

extern "C" void kernel_launch(void* const* d_in, const int* in_sizes, int n_in,
                              void* d_out, int out_size, void* d_ws, size_t ws_size,
                              hipStream_t stream) {
  char* p = (char*)d_ws;
  uint16_t* featImg = (uint16_t*)p; p += (size_t)8 * 8 * 4 * IMG * 2 + PADB;  // 37.9 MB
  uint32_t* WP = (uint32_t*)p;      p += (size_t)4 * 442368 * 4;              // 7.1 MB
  float* bp = (float*)p;            p += 4096;
  uint16_t* hf0i = (uint16_t*)p;    p += (size_t)9 * SLOTI * 2 + PADB;        // 21.3 MB
  uint16_t* hr0i = (uint16_t*)p;    p += (size_t)9 * SLOTI * 2 + PADB;        // 21.3 MB
  uint16_t* h1fi = (uint16_t*)p;    p += (size_t)2 * SLOTI * 2 + PADB;        // 4.7 MB
  float* c0f = (float*)p;           p += (size_t)4 * 2097152;                 // c states
  float* c0r = c0f + 524288;
  float* c1f = c0r + 524288;
  float* c1r = c1f + 524288;
  float* h1f8 = (float*)p;          p += 2097152;
  float* h1r8 = (float*)p;          p += 2097152;

  hipMemsetAsync(c0f, 0, (size_t)4 * 2097152, stream);
  hipMemsetAsync(hf0i, 0, (size_t)SLOTI * 2, stream);                     // hf0 slot 0
  hipMemsetAsync(hr0i + (size_t)8 * SLOTI, 0, (size_t)SLOTI * 2, stream); // hr0 slot 8
  hipMemsetAsync(h1fi, 0, (size_t)SLOTI * 2, stream);                     // h1f parity-0 slot

  pack_features<<<dim3(9248), 256, 0, stream>>>((const float*)d_in[0], featImg);

  WPackArgs wa;
  for (int combo = 0; combo < 4; ++combo) {
    const int base = 1 + combo * 4;
    wa.wih[combo] = (const float*)d_in[base];
    wa.whh[combo] = (const float*)d_in[base + 1];
    wa.bih[combo] = (const float*)d_in[base + 2];
    wa.bhh[combo] = (const float*)d_in[base + 3];
  }
  wa.wp = WP; wa.bp = bp;
  pack_weights<<<dim3(1728, 4), 256, 0, stream>>>(wa);

  constexpr int DYN_LDS = 131072;   // 2x32KB A + 4x16KB W
  (void)hipFuncSetAttribute((const void*)conv_lstm_step,
                            hipFuncAttributeMaxDynamicSharedMemorySize, DYN_LDS);

  auto mk = [&](const uint16_t* i0, int n0, const uint16_t* i1, int n1,
                const uint16_t* i2, int n2, int combo, float* cb,
                uint16_t* himg, float* hf32) {
    StepArgs s;
    s.in0 = i0; s.in1 = i1; s.in2 = i2;
    s.nc0 = n0; s.nc1 = n1; s.nc2 = n2;
    s.W = WP + (size_t)combo * 442368; s.bias = bp + combo * 256;
    s.cbuf = cb; s.himg = himg; s.hf32 = hf32;
    return s;
  };

  // Layer 0: 8 pair launches (fwd step k, rev step 7-k); 128 blocks/dir, 512 thr.
  for (int k = 0; k < 8; ++k) {
    const int tr = 7 - k;
    StepArgs f = mk(featImg + (size_t)k * 8 * 4 * IMG, 4,
                    hf0i + (size_t)k * SLOTI, 2, nullptr, 0,
                    0, c0f, hf0i + (size_t)(k + 1) * SLOTI, nullptr);
    StepArgs r = mk(featImg + (size_t)tr * 8 * 4 * IMG, 4,
                    hr0i + (size_t)(tr + 1) * SLOTI, 2, nullptr, 0,
                    1, c0r, hr0i + (size_t)tr * SLOTI, nullptr);
    conv_lstm_step<<<dim3(128, 1, 2), 512, DYN_LDS, stream>>>(f, r);
  }

  // Layer 1: fwd t=0 pairs with the single reverse step (t=7, zero init state).
  for (int t = 0; t < 8; ++t) {
    uint16_t* himg = (t < 7) ? h1fi + (size_t)((t + 1) & 1) * SLOTI : nullptr;
    float* hf32 = (t == 7) ? h1f8 : nullptr;
    StepArgs s = mk(hf0i + (size_t)(t + 1) * SLOTI, 2, hr0i + (size_t)t * SLOTI, 2,
                    h1fi + (size_t)(t & 1) * SLOTI, 2, 2, c1f, himg, hf32);
    if (t == 0) {
      StepArgs rv = mk(hf0i + (size_t)8 * SLOTI, 2, hr0i + (size_t)7 * SLOTI, 2,
                       nullptr, 0, 3, c1r, nullptr, h1r8);
      conv_lstm_step<<<dim3(128, 1, 2), 512, DYN_LDS, stream>>>(s, rv);
    } else {
      conv_lstm_step<<<dim3(128, 1, 1), 512, DYN_LDS, stream>>>(s, s);
    }
  }

  final_conv<<<dim3(32, 4), 256, 0, stream>>>(
      h1f8, h1r8, (const float*)d_in[17], (const float*)d_in[18], (float*)d_out);
}

// Round 7
// 749.957 us; speedup vs baseline: 1.0320x; 1.0320x over previous
//
#include <hip/hip_runtime.h>
#include <math.h>
#include <stdint.h>

// ConvLSTM (Seq2VecRNN2D) round 7: 4-wave blocks (wave = row-pair x hc-half,
// 4x4 frag tile), operand-tied asm fence to force read->MFMA software pipeline,
// W staged 3-ahead (4 slots), raw vmcnt+s_barrier. 3-term bf16-split MFMA.
// B=8 T=8 CIN=128 HID=64 G=256 H=W=32.
//
// Activation image per (slot,b,cg32): [34 y'][34 px][8 blk of 16B], blk = pl*4+kg
// stored at blk^(px&7); ch = cg*32+kg*8+j, pl0=hi bf16, pl1=lo bf16. Borders zero.
// Weight image per (combo,cg,tap,nt): [pl][4 g][16 hcp][8 b8 of 16B], b8 = kg+4*(hc&1)
// stored at b8^(hcp&7); hcp = hc_local>>1.
//
// Per-wave DMA per window: 4 W chunks (+ACH A chunks at tap0). In-order vmcnt:
// need W[lin+1] (staged at lin-2) before this window's reads -> CNT = 4, except
// taps 1,2 where the tap0 A-burst sits between -> CNT = 4+ACH.

typedef __attribute__((ext_vector_type(8))) short short8;
typedef __attribute__((ext_vector_type(4))) float float4v;

namespace {
constexpr int IMG = 34 * 34 * 64;            // u16 per (slot,b,cg) image
constexpr size_t SLOTI = 16ull * IMG;        // u16 per h slot (8 b x 2 cg)
constexpr int ROWB = 34 * 128;               // bytes per image row (4352)
constexpr int PADB = 8192;                   // tail slack for DMA overshoot
}
template <int N> struct IC { static constexpr int v = N; };

__device__ __forceinline__ uint16_t bf16_rne(float x) {
  uint32_t u = __builtin_bit_cast(uint32_t, x);
  return (uint16_t)((u + 0x7FFFu + ((u >> 16) & 1u)) >> 16);
}
__device__ __forceinline__ float bf16_to_f(uint16_t h) {
  uint32_t u = ((uint32_t)h) << 16;
  return __builtin_bit_cast(float, u);
}

__device__ __forceinline__ void gl_lds16(const void* g, void* l) {
  __builtin_amdgcn_global_load_lds(
      (const __attribute__((address_space(1))) void*)g,
      (__attribute__((address_space(3))) void*)l, 16, 0, 0);
}

template <int NMF> struct Frags { short8 a[NMF][2]; short8 w[2][4]; };

// Fence: ds_reads (memory) cannot sink below; MFMAs consuming f (redefined via
// "+v") cannot hoist above. Forces reads to issue before the MFMA burst.
__device__ __forceinline__ void pin_frags(Frags<4>& f) {
  asm volatile("" : "+v"(f.a[0][0]), "+v"(f.a[0][1]), "+v"(f.a[1][0]), "+v"(f.a[1][1]),
                    "+v"(f.a[2][0]), "+v"(f.a[2][1]), "+v"(f.a[3][0]), "+v"(f.a[3][1]),
                    "+v"(f.w[0][0]), "+v"(f.w[0][1]), "+v"(f.w[0][2]), "+v"(f.w[0][3]),
                    "+v"(f.w[1][0]), "+v"(f.w[1][1]), "+v"(f.w[1][2]), "+v"(f.w[1][3])
               :: "memory");
}
__device__ __forceinline__ void pin_frags(Frags<2>& f) {
  asm volatile("" : "+v"(f.a[0][0]), "+v"(f.a[0][1]), "+v"(f.a[1][0]), "+v"(f.a[1][1]),
                    "+v"(f.w[0][0]), "+v"(f.w[0][1]), "+v"(f.w[0][2]), "+v"(f.w[0][3]),
                    "+v"(f.w[1][0]), "+v"(f.w[1][1]), "+v"(f.w[1][2]), "+v"(f.w[1][3])
               :: "memory");
}

// ---- feature pack: fp32 [B][T][128][32][32] -> swizzled images [t][b][4cg] ----
__global__ void pack_features(const float* __restrict__ f, uint16_t* __restrict__ out) {
  const size_t i = (size_t)blockIdx.x * 256 + threadIdx.x;  // 16B-block index, < 2367488
  const int blk_s = (int)(i & 7);
  size_t pp = i >> 3;
  const int px = (int)(pp % 34); pp /= 34;
  const int yy = (int)(pp % 34); pp /= 34;
  const int cg = (int)(pp & 3);
  const int bt = (int)(pp >> 2);
  const int b = bt & 7, t = bt >> 3;
  const int blk = blk_s ^ (px & 7);
  const int pl = blk >> 2, kg = blk & 3;
  short8 sv;
  if (px == 0 || px == 33 || yy == 0 || yy == 33) {
    #pragma unroll
    for (int j = 0; j < 8; ++j) sv[j] = 0;
  } else {
    const int x = px - 1, y = yy - 1;
    #pragma unroll
    for (int j = 0; j < 8; ++j) {
      const int ch = cg * 32 + kg * 8 + j;
      const float fv = f[(((size_t)b * 8 + t) * 128 + ch) * 1024 + y * 32 + x];
      const uint16_t hi = bf16_rne(fv);
      sv[j] = (short)(pl ? bf16_rne(fv - bf16_to_f(hi)) : hi);
    }
  }
  *(short8*)(out + i * 8) = sv;
}

// ---- weight pack into swizzled images: per combo [cg][tap][nt][4096 u32] ----
struct WPackArgs {
  const float* wih[4]; const float* whh[4];
  const float* bih[4]; const float* bhh[4];
  uint32_t* wp; float* bp;
};
__global__ void pack_weights(WPackArgs A) {
  const int combo = blockIdx.y;
  const int idx = blockIdx.x * 256 + threadIdx.x;  // < 442368
  const int q = idx & 4095;
  const int rest = idx >> 12;
  const int nt = rest & 1;
  const int ct = rest >> 1;          // cg*9+tap
  const int tap = ct % 9, cg = ct / 9;
  const int w2 = q & 3;
  const int b8s = (q >> 2) & 7;
  const int hcp = (q >> 5) & 15;
  const int g = (q >> 9) & 3;
  const int pl = (q >> 11) & 1;
  const int b8 = b8s ^ (hcp & 7);
  const int kg = b8 & 3;
  const int hcl = hcp * 2 + (b8 >> 2);
  const int n = g * 64 + nt * 32 + hcl;
  const float* wih = A.wih[combo];
  const float* whh = A.whh[combo];
  uint32_t out = 0;
  #pragma unroll
  for (int e = 0; e < 2; ++e) {
    const int ch = cg * 32 + kg * 8 + w2 * 2 + e;
    const float wv = (ch < 128) ? wih[((size_t)n * 128 + ch) * 9 + tap]
                                : whh[((size_t)n * 64 + (ch - 128)) * 9 + tap];
    const uint16_t hi = bf16_rne(wv);
    const uint16_t v = pl ? bf16_rne(wv - bf16_to_f(hi)) : hi;
    out |= ((uint32_t)v) << (16 * e);
  }
  A.wp[(size_t)combo * 442368 + idx] = out;
  if (idx < 256) A.bp[combo * 256 + idx] = A.bih[combo][idx] + A.bhh[combo][idx];
}

struct StepArgs {
  const uint16_t* in0; const uint16_t* in1; const uint16_t* in2;  // images
  int nc0, nc1, nc2;         // cg counts per tensor
  const uint32_t* W;         // combo base: [cg][tap][nt][4096 u32]
  const float* bias;         // [256], n = gate*64+hc
  float* cbuf;               // plain fp32 [b][64][1024]
  uint16_t* himg;            // nullable: [b][2 cg][IMG]
  float* hf32;               // nullable: plain [b][64][1024]
};

// Block: 256 thr = 4 waves. wave w: hcg = w&1 (hc half), mh = w>>1 (row pair).
// Wave tile: MROWS m-frags (R rows x 2 xh) x 4 gates (x 16 hc).
template <int MROWS>
__global__ __launch_bounds__(256, 1) void conv_lstm_step(StepArgs A0, StepArgs A1) {
  constexpr int R = MROWS / 2;
  constexpr int NMF = MROWS;
  constexpr int ACH = (MROWS == 4) ? 7 : 5;        // A chunks per wave
  constexpr int NBANDS = 32 / MROWS;
  extern __shared__ char smem[];
  char* Asm_ = smem;               // 2 x 32768 (A double-buffer)
  char* Wsm_ = smem + 65536;       // 4 x 16384 (W quad-buffer)

  const StepArgs a = (blockIdx.z == 0) ? A0 : A1;
  const int bx = blockIdx.x;
  const int nt = bx & 1;
  const int band = (bx >> 1) & (NBANDS - 1);
  const int b = bx >> ((MROWS == 4) ? 4 : 5);
  const int y0 = band * MROWS;
  const int tid = threadIdx.x;
  const int lane = tid & 63;
  const int w = tid >> 6;          // 0..3
  const int m15 = lane & 15;
  const int kg = lane >> 4;
  const int hcg = w & 1;
  const int mh = w >> 1;

  // fragment read offsets (bytes), conflict-free via baked swizzle
  int offA0[2][3][2];
  #pragma unroll
  for (int xh = 0; xh < 2; ++xh)
    #pragma unroll
    for (int kx = 0; kx < 3; ++kx)
      #pragma unroll
      for (int pl = 0; pl < 2; ++pl) {
        const int px = xh * 16 + kx + m15;
        const int sw = (pl * 4 + kg) ^ (px & 7);
        offA0[xh][kx][pl] = px * 128 + sw * 16;
      }
  int offW[2][4];
  {
    const int hcp = hcg * 8 + (m15 >> 1);
    const int b8 = kg + 4 * (m15 & 1);
    #pragma unroll
    for (int pl = 0; pl < 2; ++pl)
      #pragma unroll
      for (int g = 0; g < 4; ++g)
        offW[pl][g] = (((pl * 4 + g) * 16 + hcp) * 8 + (b8 ^ (hcp & 7))) * 16;
  }
  const int mrow = mh * R * ROWB;   // wave row base within staged A

  const int ncg = a.nc0 + a.nc1 + a.nc2;
  auto abase = [&](int cg) -> const char* {
    const uint16_t* t;
    if (cg < a.nc0) t = a.in0 + ((size_t)b * a.nc0 + cg) * IMG;
    else if (cg < a.nc0 + a.nc1) t = a.in1 + ((size_t)b * a.nc1 + (cg - a.nc0)) * IMG;
    else t = a.in2 + ((size_t)b * a.nc2 + (cg - a.nc0 - a.nc1)) * IMG;
    return (const char*)t + (size_t)y0 * ROWB;
  };
  auto stageA = [&](int cgi, int par) {     // ACH chunks/wave (uniform vmcnt)
    const char* g = abase(cgi);
    char* d = Asm_ + par * 32768;
    #pragma unroll
    for (int j = 0; j < ACH; ++j)
      gl_lds16(g + (size_t)(ACH * w + j) * 1024 + lane * 16, d + (ACH * w + j) * 1024);
  };
  auto stageW = [&](int cgs, int taps, int slot) {  // 4 chunks/wave
    const char* g = (const char*)a.W + ((size_t)((cgs * 9 + taps) * 2 + nt) << 14);
    char* d = Wsm_ + slot * 16384;
    #pragma unroll
    for (int j = 0; j < 4; ++j)
      gl_lds16(g + (size_t)(4 * w + j) * 1024 + lane * 16, d + (4 * w + j) * 1024);
  };

  Frags<NMF> f0, f1;
  auto read_frags = [&](auto tnc, int par, int wslot, Frags<NMF>& f) {
    constexpr int TN = decltype(tnc)::v;
    constexpr int ky = TN / 3, kx = TN % 3;
    const char* Ab = Asm_ + par * 32768 + mrow;
    const char* Wb = Wsm_ + wslot * 16384;
    #pragma unroll
    for (int rr = 0; rr < R; ++rr)
      #pragma unroll
      for (int xh = 0; xh < 2; ++xh)
        #pragma unroll
        for (int pl = 0; pl < 2; ++pl)
          f.a[rr * 2 + xh][pl] = *(const short8*)(Ab + (rr + ky) * ROWB + offA0[xh][kx][pl]);
    #pragma unroll
    for (int pl = 0; pl < 2; ++pl)
      #pragma unroll
      for (int g = 0; g < 4; ++g)
        f.w[pl][g] = *(const short8*)(Wb + offW[pl][g]);
  };

  float4v acc[NMF][4];
  #pragma unroll
  for (int mf = 0; mf < NMF; ++mf)
    #pragma unroll
    for (int g = 0; g < 4; ++g) acc[mf][g] = (float4v){0.f, 0.f, 0.f, 0.f};

  auto do_mfma = [&](Frags<NMF>& f) {
    #pragma unroll
    for (int mf = 0; mf < NMF; ++mf)
      #pragma unroll
      for (int g = 0; g < 4; ++g) {
        acc[mf][g] = __builtin_amdgcn_mfma_f32_16x16x32_bf16(f.a[mf][0], f.w[0][g], acc[mf][g], 0, 0, 0);
        acc[mf][g] = __builtin_amdgcn_mfma_f32_16x16x32_bf16(f.a[mf][0], f.w[1][g], acc[mf][g], 0, 0, 0);
        acc[mf][g] = __builtin_amdgcn_mfma_f32_16x16x32_bf16(f.a[mf][1], f.w[0][g], acc[mf][g], 0, 0, 0);
      }
  };

  auto window = [&](auto tapc, auto parc, int cg, int lin9) {
    constexpr int TAP = decltype(tapc)::v;
    constexpr int P = decltype(parc)::v;       // parity of lin = cg*9+TAP
    constexpr int CNT = (TAP == 1 || TAP == 2) ? 4 + ACH : 4;
    asm volatile("s_waitcnt vmcnt(%0)\n\ts_barrier" :: "n"(CNT) : "memory");
    {  // stage W[lin+3] (wrap to dead-but-valid tile near the end)
      const int l3 = lin9 + TAP + 3;
      int cgs = l3 / 9;
      const int taps = l3 % 9;
      if (cgs >= ncg) cgs = 0;
      stageW(cgs, taps, l3 & 3);
    }
    if (TAP == 0) {
      const int nx = (cg + 1 < ncg) ? cg + 1 : 0;
      stageA(nx, (cg + 1) & 1);
    }
    // read next window's fragments into the other parity buffer
    constexpr int TN = (TAP + 1) % 9;
    const int cgn = cg + (TAP == 8 ? 1 : 0);
    read_frags(IC<TN>{}, cgn & 1, (lin9 + TAP + 1) & 3, P ? f0 : f1);
    Frags<NMF>& cur = P ? f1 : f0;
    pin_frags(cur);                 // reads before, MFMAs after
    do_mfma(cur);
  };
  auto run9 = [&](auto cgpc, int cg) {
    constexpr int CGP = decltype(cgpc)::v;
    const int lin9 = cg * 9;
    window(IC<0>{}, IC<(CGP + 0) & 1>{}, cg, lin9);
    window(IC<1>{}, IC<(CGP + 1) & 1>{}, cg, lin9);
    window(IC<2>{}, IC<(CGP + 2) & 1>{}, cg, lin9);
    window(IC<3>{}, IC<(CGP + 3) & 1>{}, cg, lin9);
    window(IC<4>{}, IC<(CGP + 4) & 1>{}, cg, lin9);
    window(IC<5>{}, IC<(CGP + 5) & 1>{}, cg, lin9);
    window(IC<6>{}, IC<(CGP + 6) & 1>{}, cg, lin9);
    window(IC<7>{}, IC<(CGP + 7) & 1>{}, cg, lin9);
    window(IC<8>{}, IC<(CGP + 8) & 1>{}, cg, lin9);
  };

  // Prologue: A[0]; W[0..2]. vmcnt(8) -> A0+W0 landed (W1,W2 = 8 chunks in flight).
  stageA(0, 0);
  stageW(0, 0, 0);
  stageW(0, 1, 1);
  stageW(0, 2, 2);
  asm volatile("s_waitcnt vmcnt(8)\n\ts_barrier" ::: "memory");
  read_frags(IC<0>{}, 0, 0, f0);

  for (int cg = 0; cg < ncg; ++cg) {
    if ((cg & 1) == 0) run9(IC<0>{}, cg);
    else run9(IC<1>{}, cg);
  }
  asm volatile("s_waitcnt vmcnt(0)" ::: "memory");  // drain dummy restages

  // ---- fused LSTM cell epilogue ----
  const int hcl = hcg * 16 + m15;
  const int hc = nt * 32 + hcl;
  float bi[4];
  #pragma unroll
  for (int g = 0; g < 4; ++g) bi[g] = a.bias[g * 64 + hc];
  uint16_t* hb = a.himg ? a.himg + ((size_t)(b * 2 + nt)) * IMG : nullptr;
  const int kgb = hcl >> 3, jj = hcl & 7;
  #pragma unroll
  for (int rr = 0; rr < R; ++rr) {
    const int y = y0 + mh * R + rr;
    float* crow = a.cbuf + ((size_t)(b * 64 + hc)) * 1024 + y * 32;
    float* hrow = a.hf32 ? a.hf32 + ((size_t)(b * 64 + hc)) * 1024 + y * 32 : nullptr;
    #pragma unroll
    for (int xh = 0; xh < 2; ++xh) {
      const int mf = rr * 2 + xh;
      const int x0 = xh * 16 + kg * 4;
      float4v cv = *(float4v*)(crow + x0);
      float4v cn, hn;
      #pragma unroll
      for (int q = 0; q < 4; ++q) {
        const float ig = 1.f / (1.f + expf(-(acc[mf][0][q] + bi[0])));
        const float fg = 1.f / (1.f + expf(-(acc[mf][1][q] + bi[1])));
        const float gg = tanhf(acc[mf][2][q] + bi[2]);
        const float og = 1.f / (1.f + expf(-(acc[mf][3][q] + bi[3])));
        const float c2 = fg * cv[q] + ig * gg;
        cn[q] = c2;
        hn[q] = og * tanhf(c2);
      }
      *(float4v*)(crow + x0) = cn;
      if (hrow) *(float4v*)(hrow + x0) = hn;
      if (hb) {
        #pragma unroll
        for (int q = 0; q < 4; ++q) {
          const int px = x0 + q + 1;
          const int sw = px & 7;
          const uint16_t hi = bf16_rne(hn[q]);
          const uint16_t lo = bf16_rne(hn[q] - bf16_to_f(hi));
          const size_t p16 = ((size_t)(y + 1) * 34 + px) * 64;
          hb[p16 + (size_t)(kgb ^ sw) * 8 + jj] = hi;
          hb[p16 + (size_t)((4 + kgb) ^ sw) * 8 + jj] = lo;
        }
      }
    }
  }
  if (hb) {   // keep image borders zero (ws is re-poisoned every call)
    for (int i = tid; i < MROWS * 128; i += 256) {
      const int rr = i >> 7;
      const int hlf = (i >> 6) & 1;
      const int jx = i & 63;
      hb[((size_t)(y0 + 1 + rr) * 34 + hlf * 33) * 64 + jx] = 0;
    }
    if (band == 0) for (int i = tid; i < 2176; i += 256) hb[i] = 0;
    if (band == NBANDS - 1) for (int i = tid; i < 2176; i += 256) hb[(size_t)33 * 2176 + i] = 0;
  }
}

// out[b][o][p] = relu(b_out[o] + sum_c w_out[o][c] * last[b][c][p])  (fp32 inputs)
__global__ void final_conv(const float* __restrict__ h1f_last, const float* __restrict__ h1r_last,
                           const float* __restrict__ wout, const float* __restrict__ bout,
                           float* __restrict__ out) {
  __shared__ float Ws[16 * 128];
  const int oq = blockIdx.y;
  for (int i = threadIdx.x; i < 16 * 128; i += 256) Ws[i] = wout[oq * 16 * 128 + i];
  __syncthreads();
  const int gp = blockIdx.x * 256 + threadIdx.x;
  const int b = gp >> 10, p = gp & 1023;
  float acc[16];
  #pragma unroll
  for (int o = 0; o < 16; ++o) acc[o] = bout[oq * 16 + o];
  for (int c = 0; c < 128; ++c) {
    const float xv = (c < 64) ? h1f_last[((size_t)b * 64 + c) * 1024 + p]
                              : h1r_last[((size_t)b * 64 + (c - 64)) * 1024 + p];
    #pragma unroll
    for (int o = 0; o < 16; ++o) acc[o] = fmaf(xv, Ws[o * 128 + c], acc[o]);
  }
  #pragma unroll
  for (int o = 0; o < 16; ++o) {
    const float v = acc[o];
    out[((size_t)b * 64 + oq * 16 + o) * 1024 + p] = v > 0.f ? v : 0.f;
  }
}

extern "C" void kernel_launch(void* const* d_in, const int* in_sizes, int n_in,
                              void* d_out, int out_size, void* d_ws, size_t ws_size,
                              hipStream_t stream) {
  char* p = (char*)d_ws;
  uint16_t* featImg = (uint16_t*)p; p += (size_t)8 * 8 * 4 * IMG * 2 + PADB;  // 37.9 MB
  uint32_t* WP = (uint32_t*)p;      p += (size_t)4 * 442368 * 4;              // 7.1 MB
  float* bp = (float*)p;            p += 4096;
  uint16_t* hf0i = (uint16_t*)p;    p += (size_t)9 * SLOTI * 2 + PADB;        // 21.3 MB
  uint16_t* hr0i = (uint16_t*)p;    p += (size_t)9 * SLOTI * 2 + PADB;        // 21.3 MB
  uint16_t* h1fi = (uint16_t*)p;    p += (size_t)2 * SLOTI * 2 + PADB;        // 4.7 MB
  float* c0f = (float*)p;           p += (size_t)4 * 2097152;                 // c states
  float* c0r = c0f + 524288;
  float* c1f = c0r + 524288;
  float* c1r = c1f + 524288;
  float* h1f8 = (float*)p;          p += 2097152;
  float* h1r8 = (float*)p;          p += 2097152;

  hipMemsetAsync(c0f, 0, (size_t)4 * 2097152, stream);
  hipMemsetAsync(hf0i, 0, (size_t)SLOTI * 2, stream);                     // hf0 slot 0
  hipMemsetAsync(hr0i + (size_t)8 * SLOTI, 0, (size_t)SLOTI * 2, stream); // hr0 slot 8
  hipMemsetAsync(h1fi, 0, (size_t)SLOTI * 2, stream);                     // h1f parity-0 slot

  pack_features<<<dim3(9248), 256, 0, stream>>>((const float*)d_in[0], featImg);

  WPackArgs wa;
  for (int combo = 0; combo < 4; ++combo) {
    const int base = 1 + combo * 4;
    wa.wih[combo] = (const float*)d_in[base];
    wa.whh[combo] = (const float*)d_in[base + 1];
    wa.bih[combo] = (const float*)d_in[base + 2];
    wa.bhh[combo] = (const float*)d_in[base + 3];
  }
  wa.wp = WP; wa.bp = bp;
  pack_weights<<<dim3(1728, 4), 256, 0, stream>>>(wa);

  constexpr int DYN_LDS = 131072;   // 2x32KB A + 4x16KB W
  (void)hipFuncSetAttribute((const void*)conv_lstm_step<4>,
                            hipFuncAttributeMaxDynamicSharedMemorySize, DYN_LDS);
  (void)hipFuncSetAttribute((const void*)conv_lstm_step<2>,
                            hipFuncAttributeMaxDynamicSharedMemorySize, DYN_LDS);

  auto mk = [&](const uint16_t* i0, int n0, const uint16_t* i1, int n1,
                const uint16_t* i2, int n2, int combo, float* cb,
                uint16_t* himg, float* hf32) {
    StepArgs s;
    s.in0 = i0; s.in1 = i1; s.in2 = i2;
    s.nc0 = n0; s.nc1 = n1; s.nc2 = n2;
    s.W = WP + (size_t)combo * 442368; s.bias = bp + combo * 256;
    s.cbuf = cb; s.himg = himg; s.hf32 = hf32;
    return s;
  };

  // Layer 0: 8 pair launches (fwd step k, rev step 7-k); MROWS=4, 128 blocks/dir.
  for (int k = 0; k < 8; ++k) {
    const int tr = 7 - k;
    StepArgs f = mk(featImg + (size_t)k * 8 * 4 * IMG, 4,
                    hf0i + (size_t)k * SLOTI, 2, nullptr, 0,
                    0, c0f, hf0i + (size_t)(k + 1) * SLOTI, nullptr);
    StepArgs r = mk(featImg + (size_t)tr * 8 * 4 * IMG, 4,
                    hr0i + (size_t)(tr + 1) * SLOTI, 2, nullptr, 0,
                    1, c0r, hr0i + (size_t)tr * SLOTI, nullptr);
    conv_lstm_step<4><<<dim3(128, 1, 2), 256, DYN_LDS, stream>>>(f, r);
  }

  // Layer 1: MROWS=2, 256 blocks/dir; fwd t=0 pairs with the single reverse step.
  for (int t = 0; t < 8; ++t) {
    uint16_t* himg = (t < 7) ? h1fi + (size_t)((t + 1) & 1) * SLOTI : nullptr;
    float* hf32 = (t == 7) ? h1f8 : nullptr;
    StepArgs s = mk(hf0i + (size_t)(t + 1) * SLOTI, 2, hr0i + (size_t)t * SLOTI, 2,
                    h1fi + (size_t)(t & 1) * SLOTI, 2, 2, c1f, himg, hf32);
    if (t == 0) {
      StepArgs rv = mk(hf0i + (size_t)8 * SLOTI, 2, hr0i + (size_t)7 * SLOTI, 2,
                       nullptr, 0, 3, c1r, nullptr, h1r8);
      conv_lstm_step<2><<<dim3(256, 1, 2), 256, DYN_LDS, stream>>>(s, rv);
    } else {
      conv_lstm_step<2><<<dim3(256, 1, 1), 256, DYN_LDS, stream>>>(s, s);
    }
  }

  final_conv<<<dim3(32, 4), 256, 0, stream>>>(
      h1f8, h1r8, (const float*)d_in[17], (const float*)d_in[18], (float*)d_out);
}